// Round 1
// 116.703 us; speedup vs baseline: 1.0405x; 1.0405x over previous
//
#include <hip/hip_runtime.h>
#include <hip/hip_bf16.h>

typedef __attribute__((ext_vector_type(8))) short short8;
typedef __attribute__((ext_vector_type(4))) float f32x4;
using bf16 = __hip_bfloat16;

__device__ __forceinline__ unsigned short f2bf(float f) {
    unsigned u = __float_as_uint(f);
    u += 0x7fff + ((u >> 16) & 1);           // round-to-nearest-even
    return (unsigned short)(u >> 16);
}
__device__ __forceinline__ float bf2f(unsigned short s) {
    return __uint_as_float(((unsigned)s) << 16);
}
// async global->LDS DMA, 16B/lane; global lane addrs CONTIGUOUS (packed layout)
__device__ __forceinline__ void gl_lds16(const unsigned short* g, unsigned short* l) {
    __builtin_amdgcn_global_load_lds(
        (const __attribute__((address_space(1))) unsigned int*)g,
        (__attribute__((address_space(3))) unsigned int*)l, 16, 0, 0);
}

// Packed layout (shorts): off = ((g*64 + s)*64 + r)*8   g=row/64, s=k/8, r=row%64
// => a wave staging (g, s, rows 0..63) reads 64 lanes x 16B = 1KB contiguous.

// ---------------------------------------------------------------- pack fp32 -> packed bf16 (+ zero ssq)
__global__ __launch_bounds__(256) void pack_kernel(
    const float* __restrict__ X, const float* __restrict__ Wq, const float* __restrict__ Wk,
    const float* __restrict__ Wv, const float* __restrict__ Wo,
    bf16* __restrict__ Xp, bf16* __restrict__ Wqp, bf16* __restrict__ Wkp,
    bf16* __restrict__ Wvp, bf16* __restrict__ Wop, float* __restrict__ ssq)
{
    __shared__ __align__(16) unsigned short sm[4096];   // [s_local 8][r 64][8]
    int id = blockIdx.x;
    int tid = threadIdx.x;
    if (id < 8) {
        int zi = id * 1024 + tid * 4;
        *(float4*)&ssq[zi] = make_float4(0.f, 0.f, 0.f, 0.f);
    }
    const float* src; unsigned short* dst; int g, sc;
    if (id < 512) { src = X; dst = (unsigned short*)Xp; g = id >> 3; sc = id & 7; }
    else {
        int t = id - 512; int wsel = t >> 6; int u = t & 63;
        g = u >> 3; sc = u & 7;
        src = (wsel == 0) ? Wq : ((wsel == 1) ? Wk : ((wsel == 2) ? Wv : Wo));
        dst = (unsigned short*)((wsel == 0) ? Wqp : ((wsel == 1) ? Wkp : ((wsel == 2) ? Wvp : Wop)));
    }
    int r = tid >> 2, kq = tid & 3;          // 64 rows x 4 k-chunks of 16
    const float* sp = src + (size_t)(g * 64 + r) * 512 + sc * 64 + kq * 16;
    #pragma unroll
    for (int i = 0; i < 4; ++i) {
        float4 v = *(const float4*)(sp + i * 4);
        int kk = kq * 16 + i * 4;            // local k 0..63
        int sl = kk >> 3, el = kk & 7;       // el in {0,4}
        ushort4 u4;
        u4.x = f2bf(v.x); u4.y = f2bf(v.y); u4.z = f2bf(v.z); u4.w = f2bf(v.w);
        *(ushort4*)&sm[(sl * 64 + r) * 8 + el] = u4;
    }
    __syncthreads();
    unsigned short* dp = dst + (size_t)g * 32768 + sc * 4096;   // 8 s-values contiguous
    *(uint4*)(dp + tid * 16)     = *(const uint4*)&sm[tid * 16];
    *(uint4*)(dp + tid * 16 + 8) = *(const uint4*)&sm[tid * 16 + 8];
}

// ---------------------------------------------------------------- QKV GEMM (packed bf16 in, bf16 out + sumsq)
// v2: BK=64, double-buffered LDS, T3 2-phase schedule (stage next || compute cur, ONE barrier/iter).
// Out(z) = act(x @ W(z)^T + b(z)) bf16; z<2 accumulates per-row sumsq (post-relu) into ssq[z*4096+row].
// Tile 64x128; staging = pure global_load_lds_dwordx4 (6/wave/iter).  Grid (64,4,3) = 768 blocks = 3/CU.
__global__ __launch_bounds__(256) void qkv_gemm_kernel(
    const bf16* __restrict__ Xp,
    const bf16* __restrict__ W0p, const bf16* __restrict__ W1p, const bf16* __restrict__ W2p,
    const float* __restrict__ b0, const float* __restrict__ b1, const float* __restrict__ b2,
    bf16* __restrict__ O0, bf16* __restrict__ O1, bf16* __restrict__ O2,
    float* __restrict__ ssq)
{
    // 48KB: 2 buffers x (As[8][64][8] = 4096 shorts + Bs[16][64][8] = 8192 shorts)
    __shared__ __align__(16) unsigned short smem[24576];
    int z = blockIdx.z;
    const unsigned short* Wg = (const unsigned short*)((z == 0) ? W0p : ((z == 1) ? W1p : W2p));
    const float* bias = (z == 0) ? b0 : ((z == 1) ? b1 : b2);
    unsigned short* Out = (unsigned short*)((z == 0) ? O0 : ((z == 1) ? O1 : O2));
    const unsigned short* Ag = (const unsigned short*)Xp;

    int g  = blockIdx.x;              // m-group (64 rows)
    int gB = blockIdx.y * 2;          // two 64-row W groups = 128 n
    int m0 = g * 64;
    int n0 = blockIdx.y * 128;
    int tid = threadIdx.x;
    int lane = tid & 63;
    int w = tid >> 6;
    int wm = (w >> 1) * 32;
    int wn = (w & 1) * 64;
    int fr = lane & 15, qf = lane >> 4;

    f32x4 zero4 = {0.f, 0.f, 0.f, 0.f};
    f32x4 acc[2][4];
    #pragma unroll
    for (int t = 0; t < 2; ++t)
        #pragma unroll
        for (int u = 0; u < 4; ++u) acc[t][u] = zero4;

    // stage one BK=64 tile into buffer `buf`: A 8 chunks (2/wave), B 16 chunks (4/wave)
#define QKV_STAGE(buf, it) do {                                                             \
        unsigned short* As_ = smem + (buf) * 12288;                                         \
        unsigned short* Bs_ = As_ + 4096;                                                   \
        int s0_ = (it) * 8;                                                                 \
        gl_lds16(Ag + ((size_t)(g * 64 + s0_ + w * 2)     * 64 + lane) * 8, As_ + w * 1024);        \
        gl_lds16(Ag + ((size_t)(g * 64 + s0_ + w * 2 + 1) * 64 + lane) * 8, As_ + w * 1024 + 512);  \
        gl_lds16(Wg + ((size_t)((gB + (w >> 1)) * 64 + s0_ + (w & 1) * 4)     * 64 + lane) * 8, Bs_ + (w * 4)     * 512); \
        gl_lds16(Wg + ((size_t)((gB + (w >> 1)) * 64 + s0_ + (w & 1) * 4 + 1) * 64 + lane) * 8, Bs_ + (w * 4 + 1) * 512); \
        gl_lds16(Wg + ((size_t)((gB + (w >> 1)) * 64 + s0_ + (w & 1) * 4 + 2) * 64 + lane) * 8, Bs_ + (w * 4 + 2) * 512); \
        gl_lds16(Wg + ((size_t)((gB + (w >> 1)) * 64 + s0_ + (w & 1) * 4 + 3) * 64 + lane) * 8, Bs_ + (w * 4 + 3) * 512); \
    } while (0)

    int cur = 0;
    QKV_STAGE(0, 0);
    __syncthreads();
    for (int it = 0; it < 8; ++it) {
        if (it < 7) QKV_STAGE(cur ^ 1, it + 1);     // prefetch issues overlap compute below
        const unsigned short* As = smem + cur * 12288;
        const unsigned short* Bs = As + 4096;
        #pragma unroll
        for (int kk = 0; kk < 2; ++kk) {
            short8 af[2], bfr[4];
            #pragma unroll
            for (int t = 0; t < 2; ++t)
                af[t] = *(const short8*)&As[((kk * 4 + qf) * 64 + wm + t * 16 + fr) * 8];
            #pragma unroll
            for (int u = 0; u < 4; ++u)
                bfr[u] = *(const short8*)&Bs[(((w & 1) * 8 + kk * 4 + qf) * 64 + u * 16 + fr) * 8];
            #pragma unroll
            for (int t = 0; t < 2; ++t)
                #pragma unroll
                for (int u = 0; u < 4; ++u)
                    acc[t][u] = __builtin_amdgcn_mfma_f32_16x16x32_bf16(af[t], bfr[u], acc[t][u], 0, 0, 0);
        }
        __syncthreads();    // drains prefetch (vmcnt0) + guards buffer reuse; ONE barrier/iter
        cur ^= 1;
    }
#undef QKV_STAGE

    bool relu = (z < 2);
    int rb = qf * 4;
    #pragma unroll
    for (int t = 0; t < 2; ++t)
        #pragma unroll
        for (int u = 0; u < 4; ++u) {
            float bv = bias[n0 + wn + u * 16 + fr];
            #pragma unroll
            for (int r = 0; r < 4; ++r) {
                float v = acc[t][u][r] + bv;
                if (relu) v = fmaxf(v, 0.f);
                acc[t][u][r] = v;
            }
        }
    if (relu) {
        #pragma unroll
        for (int t = 0; t < 2; ++t)
            #pragma unroll
            for (int r = 0; r < 4; ++r) {
                float s = 0.f;
                #pragma unroll
                for (int u = 0; u < 4; ++u) s += acc[t][u][r] * acc[t][u][r];
                #pragma unroll
                for (int off = 1; off < 16; off <<= 1) s += __shfl_xor(s, off, 64);
                if (fr == 0) atomicAdd(&ssq[z * 4096 + m0 + wm + t * 16 + rb + r], s);
            }
    }
    // final loop barrier already drained all LDS reads -> stage C [row][128] directly
    #pragma unroll
    for (int t = 0; t < 2; ++t)
        #pragma unroll
        for (int u = 0; u < 4; ++u)
            #pragma unroll
            for (int r = 0; r < 4; ++r)
                smem[(wm + t * 16 + rb + r) * 128 + wn + u * 16 + fr] = f2bf(acc[t][u][r]);
    __syncthreads();
    #pragma unroll
    for (int rep = 0; rep < 4; ++rep) {
        int idx8 = rep * 256 + tid;
        int row = idx8 >> 4, col8 = (idx8 & 15) * 8;
        *(uint4*)(Out + (size_t)(m0 + row) * 512 + n0 + col8) = *(const uint4*)&smem[row * 128 + col8];
    }
}

// ---------------------------------------------------------------- per-chunk (64 rows) KV sums + scaled V^T
// ScT[(n*32+c)*4096 + m*64 + d] = sum_{j in 64-chunk c} k[j][d]*v'[j][m], v' = v/|k_row|
// Vt_g[n][m][l] = v'[l][m] bf16.   Grid 512 = (n 16, c 32) -> 2 blocks/CU.
__global__ __launch_bounds__(256) void chunk_kv_kernel(
    const bf16* __restrict__ Kb, const bf16* __restrict__ Vb,
    const float* __restrict__ ssq, float* __restrict__ ScT, bf16* __restrict__ Vt_g)
{
    int n = blockIdx.x >> 5, c = blockIdx.x & 31;
    int b = n >> 3, h = n & 7;
    __shared__ float Ks[64 * 64];
    __shared__ float Vs[64 * 64];
    const unsigned short* Kg = (const unsigned short*)Kb;
    const unsigned short* Vg = (const unsigned short*)Vb;
    int tid = threadIdx.x;
    int td = tid >> 4, tm = tid & 15;
    int d0 = td * 4, m0 = tm * 4;
    #pragma unroll
    for (int rep = 0; rep < 4; ++rep) {
        int idx = rep * 1024 + tid * 4;
        int j = idx >> 6, d = idx & 63;
        int grow = (c * 64 + j) * 2 + b;
        ushort4 ku = *(const ushort4*)&Kg[(size_t)grow * 512 + h * 64 + d];
        ushort4 vu = *(const ushort4*)&Vg[(size_t)grow * 512 + h * 64 + d];
        float rk = 1.f / fmaxf(sqrtf(ssq[4096 + grow]), 1e-12f);
        *(float4*)&Ks[j * 64 + d] = make_float4(bf2f(ku.x), bf2f(ku.y), bf2f(ku.z), bf2f(ku.w));
        *(float4*)&Vs[j * 64 + d] = make_float4(bf2f(vu.x) * rk, bf2f(vu.y) * rk,
                                                bf2f(vu.z) * rk, bf2f(vu.w) * rk);
    }
    __syncthreads();
    float acc[4][4] = {};
    for (int j = 0; j < 64; ++j) {
        float4 kv = *(const float4*)&Ks[j * 64 + d0];
        float4 vv = *(const float4*)&Vs[j * 64 + m0];
        acc[0][0] += kv.x*vv.x; acc[0][1] += kv.x*vv.y; acc[0][2] += kv.x*vv.z; acc[0][3] += kv.x*vv.w;
        acc[1][0] += kv.y*vv.x; acc[1][1] += kv.y*vv.y; acc[1][2] += kv.y*vv.z; acc[1][3] += kv.y*vv.w;
        acc[2][0] += kv.z*vv.x; acc[2][1] += kv.z*vv.y; acc[2][2] += kv.z*vv.z; acc[2][3] += kv.z*vv.w;
        acc[3][0] += kv.w*vv.x; acc[3][1] += kv.w*vv.y; acc[3][2] += kv.w*vv.z; acc[3][3] += kv.w*vv.w;
    }
    // scaled V^T bf16: thread -> m = tid&63, 16 j's starting at (tid>>6)*16
    int vm = tid & 63, vj0 = (tid >> 6) * 16;
    unsigned short tmp[16];
    #pragma unroll
    for (int i = 0; i < 16; ++i) tmp[i] = f2bf(Vs[(vj0 + i) * 64 + vm]);
    size_t vtoff = (size_t)n * 131072 + (size_t)vm * 2048 + c * 64 + vj0;
    *(uint4*)((unsigned short*)Vt_g + vtoff)     = *(uint4*)&tmp[0];
    *(uint4*)((unsigned short*)Vt_g + vtoff + 8) = *(uint4*)&tmp[8];

    float* outp = ScT + (size_t)blockIdx.x * 4096;
    #pragma unroll
    for (int j2 = 0; j2 < 4; ++j2) {
        float4 o4 = make_float4(acc[0][j2], acc[1][j2], acc[2][j2], acc[3][j2]);
        *(float4*)&outp[(m0 + j2) * 64 + d0] = o4;
    }
}

// ---------------------------------------------------------------- exclusive chunk prefix (32 planes) -> SpT bf16
__global__ __launch_bounds__(256) void prefix_kernel(const float* __restrict__ ScT, bf16* __restrict__ SpT)
{
    int n = blockIdx.x >> 4;
    int idx = ((blockIdx.x & 15) << 8) + threadIdx.x;   // 0..4095 within plane
    size_t base = (size_t)n * 131072 + idx;
    unsigned short* sp = (unsigned short*)SpT;
    float run = 0.f;
    #pragma unroll
    for (int c = 0; c < 32; ++c) {
        size_t off = base + (size_t)c * 4096;
        sp[off] = f2bf(run);
        run += ScT[off];
    }
}

// ---------------------------------------------------------------- MFMA causal linear attention per (head, 64-chunk)
// out[l] = (1/|q_l|) * [ q_l @ Sprev + sum_{j<=l in chunk} (q_l . k_j) v'_j ].  Grid 512 -> 2 blocks/CU.
// Output written in PACKED layout for oproj's global_load_lds: group g' = c*2+b, r = l, s = h*8..h*8+7.
__global__ __launch_bounds__(256) void attn_kernel(
    const bf16* __restrict__ Qb, const bf16* __restrict__ Kb,
    const bf16* __restrict__ Vt_g, const bf16* __restrict__ SpT_g,
    const float* __restrict__ ssq, bf16* __restrict__ AOb)
{
    int n = blockIdx.x >> 5, c = blockIdx.x & 31;
    int b = n >> 3, h = n & 7;
    __shared__ __align__(16) unsigned short Qs[64 * 72];   // [l][d]
    __shared__ __align__(16) unsigned short Ks[64 * 72];   // [j][d]
    __shared__ __align__(16) unsigned short Vt[64 * 72];   // [m][j]
    __shared__ __align__(16) unsigned short Ps[4 * 16 * 40];
    int tid = threadIdx.x;
    int lane = tid & 63;
    int w = tid >> 6;
    int fr = lane & 15, q = lane >> 4;

    const unsigned short* Qg = (const unsigned short*)Qb;
    const unsigned short* Kg = (const unsigned short*)Kb;
    const unsigned short* Vg = (const unsigned short*)Vt_g;

    #pragma unroll
    for (int rep = 0; rep < 2; ++rep) {
        int idx = rep * 256 + tid;
        int l = idx >> 3, dc = (idx & 7) * 8;
        size_t goff = (size_t)((c * 64 + l) * 2 + b) * 512 + h * 64 + dc;
        *(uint4*)&Qs[l * 72 + dc] = *(const uint4*)(Qg + goff);
        *(uint4*)&Ks[l * 72 + dc] = *(const uint4*)(Kg + goff);
        int m = l, jc = dc;
        *(uint4*)&Vt[m * 72 + jc] =
            *(const uint4*)(Vg + (size_t)n * 131072 + (size_t)m * 2048 + c * 64 + jc);
    }
    __syncthreads();

    short8 qf[2];
    #pragma unroll
    for (int kh = 0; kh < 2; ++kh)
        qf[kh] = *(const short8*)&Qs[(w * 16 + fr) * 72 + kh * 32 + q * 8];

    f32x4 zero4 = {0.f, 0.f, 0.f, 0.f};
    f32x4 oacc[4];
    #pragma unroll
    for (int mt = 0; mt < 4; ++mt) oacc[mt] = zero4;

    // O = Q @ Sprev^T (one 64x64 bf16 plane, L2-hot)
    const unsigned short* spg = (const unsigned short*)SpT_g + (size_t)blockIdx.x * 4096;
    #pragma unroll
    for (int mt = 0; mt < 4; ++mt) {
        #pragma unroll
        for (int kh = 0; kh < 2; ++kh) {
            short8 sf = *(const short8*)&spg[(mt * 16 + fr) * 64 + kh * 32 + q * 8];
            oacc[mt] = __builtin_amdgcn_mfma_f32_16x16x32_bf16(qf[kh], sf, oacc[mt], 0, 0, 0);
        }
    }

    unsigned short* myPs = &Ps[w * 640];      // 16 x 40
    int rbase = q * 4;
    int njt = (w >> 1) + 1;                   // 32-wide j-tiles needed by this wave
    for (int jt = 0; jt < njt; ++jt) {        // wave-uniform; barrier-free
        f32x4 pacc[2];
        pacc[0] = zero4; pacc[1] = zero4;
        #pragma unroll
        for (int jt16 = 0; jt16 < 2; ++jt16) {
            #pragma unroll
            for (int kh = 0; kh < 2; ++kh) {
                short8 kf = *(const short8*)&Ks[(jt * 32 + jt16 * 16 + fr) * 72 + kh * 32 + q * 8];
                pacc[jt16] = __builtin_amdgcn_mfma_f32_16x16x32_bf16(qf[kh], kf, pacc[jt16], 0, 0, 0);
            }
        }
        bool diag = (jt == njt - 1);
        int lloc = w * 16 + rbase;            // + r
        #pragma unroll
        for (int jt16 = 0; jt16 < 2; ++jt16)
            #pragma unroll
            for (int r = 0; r < 4; ++r) {
                int jl = jt * 32 + jt16 * 16 + fr;
                float pv = pacc[jt16][r];
                if (diag && jl > lloc + r) pv = 0.f;
                myPs[(rbase + r) * 40 + jt16 * 16 + fr] = f2bf(pv);
            }
        short8 pf = *(const short8*)&myPs[fr * 40 + q * 8];
        #pragma unroll
        for (int mt = 0; mt < 4; ++mt) {
            short8 vf = *(const short8*)&Vt[(mt * 16 + fr) * 72 + jt * 32 + q * 8];
            oacc[mt] = __builtin_amdgcn_mfma_f32_16x16x32_bf16(pf, vf, oacc[mt], 0, 0, 0);
        }
    }

    // scale rows by 1/|q_l|, stage, PACKED coalesced store (1KB contiguous per (g',s) cell group)
    float rqv[4];
    #pragma unroll
    for (int r = 0; r < 4; ++r) {
        int flat = (c * 64 + w * 16 + rbase + r) * 2 + b;
        rqv[r] = 1.f / fmaxf(sqrtf(ssq[flat]), 1e-12f);
    }
    __syncthreads();                          // Qs dead -> O staging [l][m] stride 64
    #pragma unroll
    for (int mt = 0; mt < 4; ++mt)
        #pragma unroll
        for (int r = 0; r < 4; ++r)
            Qs[(w * 16 + rbase + r) * 64 + mt * 16 + fr] = f2bf(oacc[mt][r] * rqv[r]);
    __syncthreads();
    // packed cell ((g'*64 + s)*64 + r)*8 with g' = c*2+b, r = l, s = h*8 + sl
    #pragma unroll
    for (int rep = 0; rep < 2; ++rep) {
        int idx8 = rep * 256 + tid;
        int sl = idx8 >> 6, l = idx8 & 63;
        *(uint4*)((unsigned short*)AOb +
                  (size_t)(((c * 2 + b) * 64 + h * 8 + sl) * 64 + l) * 8) =
            *(const uint4*)&Qs[l * 64 + sl * 8];
    }
}

// ---------------------------------------------------------------- output projection: 64x64 tile, grid (64,8)=512
// v2: A (packed by attn) and W both staged via global_load_lds; BK=64 double-buffered 2-phase.
// blockIdx.x = packed A group g' (c = g'>>1, b = g'&1, mem row = c*128 + 2l + b).
__global__ __launch_bounds__(256) void oproj_kernel(
    const bf16* __restrict__ A, const bf16* __restrict__ Wop,
    const float* __restrict__ bias, float* __restrict__ Out)
{
    // 32KB: 2 buffers x (As[8][64][8] + Bs[8][64][8]); epilogue Cf 64x64 f32 (16KB) reuses buf0
    __shared__ __align__(16) unsigned short smem[16384];
    const unsigned short* Ag = (const unsigned short*)A;
    const unsigned short* Wg = (const unsigned short*)Wop;
    int gp = blockIdx.x;              // packed A group
    int gy = blockIdx.y;
    int n0 = gy * 64;
    int tid = threadIdx.x;
    int lane = tid & 63;
    int w = tid >> 6;
    int fr = lane & 15, qf = lane >> 4;
    int wm = (w >> 1) * 32;
    int wn = (w & 1) * 32;

    f32x4 zero4 = {0.f, 0.f, 0.f, 0.f};
    f32x4 acc[2][2];
    acc[0][0] = zero4; acc[0][1] = zero4; acc[1][0] = zero4; acc[1][1] = zero4;

#define OPJ_STAGE(buf, it) do {                                                             \
        unsigned short* As_ = smem + (buf) * 8192;                                          \
        unsigned short* Bs_ = As_ + 4096;                                                   \
        int s0_ = (it) * 8;                                                                 \
        gl_lds16(Ag + ((size_t)(gp * 64 + s0_ + w * 2)     * 64 + lane) * 8, As_ + w * 1024);        \
        gl_lds16(Ag + ((size_t)(gp * 64 + s0_ + w * 2 + 1) * 64 + lane) * 8, As_ + w * 1024 + 512);  \
        gl_lds16(Wg + ((size_t)(gy * 64 + s0_ + w * 2)     * 64 + lane) * 8, Bs_ + w * 1024);        \
        gl_lds16(Wg + ((size_t)(gy * 64 + s0_ + w * 2 + 1) * 64 + lane) * 8, Bs_ + w * 1024 + 512);  \
    } while (0)

    int cur = 0;
    OPJ_STAGE(0, 0);
    __syncthreads();
    for (int it = 0; it < 8; ++it) {
        if (it < 7) OPJ_STAGE(cur ^ 1, it + 1);
        const unsigned short* As = smem + cur * 8192;
        const unsigned short* Bs = As + 4096;
        #pragma unroll
        for (int kk = 0; kk < 2; ++kk) {
            short8 af[2], bf[2];
            #pragma unroll
            for (int t = 0; t < 2; ++t)
                af[t] = *(const short8*)&As[((kk * 4 + qf) * 64 + wm + t * 16 + fr) * 8];
            #pragma unroll
            for (int u = 0; u < 2; ++u)
                bf[u] = *(const short8*)&Bs[((kk * 4 + qf) * 64 + wn + u * 16 + fr) * 8];
            #pragma unroll
            for (int t = 0; t < 2; ++t)
                #pragma unroll
                for (int u = 0; u < 2; ++u)
                    acc[t][u] = __builtin_amdgcn_mfma_f32_16x16x32_bf16(af[t], bf[u], acc[t][u], 0, 0, 0);
        }
        __syncthreads();
        cur ^= 1;
    }
#undef OPJ_STAGE

    int rb = qf * 4;
    float* Cf = (float*)smem;          // 64 x 64 fp32 (final loop barrier already drained reads)
    #pragma unroll
    for (int t = 0; t < 2; ++t)
        #pragma unroll
        for (int u = 0; u < 2; ++u) {
            float bv = bias[n0 + wn + u * 16 + fr];
            #pragma unroll
            for (int r = 0; r < 4; ++r)
                Cf[(wm + t * 16 + rb + r) * 64 + wn + u * 16 + fr] = acc[t][u][r] + bv;
        }
    __syncthreads();
    int cbase = (gp >> 1) * 128, bb = gp & 1;
    #pragma unroll
    for (int rep = 0; rep < 4; ++rep) {
        int idx = rep * 256 + tid;
        int l2 = idx >> 4, c4 = (idx & 15) * 4;
        *(float4*)(Out + (size_t)(cbase + l2 * 2 + bb) * 512 + n0 + c4) = *(const float4*)&Cf[l2 * 64 + c4];
    }
}

// ---------------------------------------------------------------- launch
extern "C" void kernel_launch(void* const* d_in, const int* in_sizes, int n_in,
                              void* d_out, int out_size, void* d_ws, size_t ws_size,
                              hipStream_t stream)
{
    (void)in_sizes; (void)n_in; (void)out_size; (void)ws_size;
    const float* x  = (const float*)d_in[0];
    const float* Wq = (const float*)d_in[1];
    const float* bq = (const float*)d_in[2];
    const float* Wk = (const float*)d_in[3];
    const float* bk = (const float*)d_in[4];
    const float* Wv = (const float*)d_in[5];
    const float* bv = (const float*)d_in[6];
    const float* Wo = (const float*)d_in[7];
    const float* bo = (const float*)d_in[8];
    float* out = (float*)d_out;

    float* ssq = (float*)d_ws;            // 8192 f32
    bf16* Xp  = (bf16*)(ssq + 8192);      // packed 4096x512
    bf16* Wqp = Xp + 2097152;             // packed 512x512 each
    bf16* Wkp = Wqp + 262144;
    bf16* Wvp = Wkp + 262144;
    bf16* Wop = Wvp + 262144;
    bf16* Qb  = Wop + 262144;             // row-major bf16 q/k/v
    bf16* Kb  = Qb + 2097152;
    bf16* Vb  = Kb + 2097152;
    bf16* Vt  = Vb + 2097152;             // 16*64*2048
    bf16* AOb = Vt + 2097152;             // PACKED attn output (g'=c*2+b, r=l)
    bf16* SpT = AOb + 2097152;            // 16*32*4096 bf16
    float* ScT = (float*)(SpT + 2097152); // 16*32*4096 f32

    pack_kernel<<<768, 256, 0, stream>>>(x, Wq, Wk, Wv, Wo, Xp, Wqp, Wkp, Wvp, Wop, ssq);
    qkv_gemm_kernel<<<dim3(64, 4, 3), 256, 0, stream>>>(Xp, Wqp, Wkp, Wvp, bq, bk, bv, Qb, Kb, Vb, ssq);
    chunk_kv_kernel<<<dim3(512), 256, 0, stream>>>(Kb, Vb, ssq, ScT, Vt);
    prefix_kernel<<<dim3(256), 256, 0, stream>>>(ScT, SpT);
    attn_kernel<<<dim3(512), 256, 0, stream>>>(Qb, Kb, Vt, SpT, ssq, AOb);
    oproj_kernel<<<dim3(64, 8), 256, 0, stream>>>(AOb, Wop, bo, out);
}